// Round 4
// baseline (171.224 us; speedup 1.0000x reference)
//
#include <hip/hip_runtime.h>

// Problem geometry (compile-time constants from the reference)
#define N_TOTAL 500000
#define C 128
#define G 32
#define NB 8
#define EPS 1e-5f
#define NBLK 2048

typedef float f4 __attribute__((ext_vector_type(4)));  // native vec for nontemporal builtins

// cumulative boundaries of LENGTHS = {40000,55000,70000,45000,80000,65000,90000,55000}
__device__ __forceinline__ int cloud_of(int i) {
    int c = 0;
    c += (i >= 40000);
    c += (i >= 95000);
    c += (i >= 165000);
    c += (i >= 210000);
    c += (i >= 290000);
    c += (i >= 355000);
    c += (i >= 445000);
    return c;
}

// element counts per (cloud, group) = LENGTHS[b] * (C/G)
__device__ const float d_cnt[NB] = {160000.f, 220000.f, 280000.f, 180000.f,
                                    320000.f, 260000.f, 360000.f, 220000.f};

// ws layout: float ws[0..255]=sum[cloud][group], ws[256..511]=sumsq;
// cid = (uint8*)ws + 4096, N_TOTAL bytes: cloud id per ORIGINAL row index.

// Pass A: zero stats + scatter cloud ids (cid[perm[i]] = cloud_of(i)).
// Only ~2.5 MB of traffic.
__global__ __launch_bounds__(256) void gn_prep(const int* __restrict__ perm,
                                               unsigned char* __restrict__ cid,
                                               float* __restrict__ ws) {
    int gid = blockIdx.x * 256 + threadIdx.x;
    if (gid < 2 * NB * G) ws[gid] = 0.f;
    int stride = gridDim.x * 256;
    for (int i = gid; i < N_TOTAL; i += stride)
        cid[perm[i]] = (unsigned char)cloud_of(i);
}

// Pass B: sequential streaming stats. Each thread owns one float4 (one group)
// of 1 row per iter; 8 per-cloud register buckets, compile-time indexed.
__global__ __launch_bounds__(256) void gn_stats(const float* __restrict__ feats,
                                                const unsigned char* __restrict__ cid,
                                                float* __restrict__ ws,
                                                int rows_per_block) {
    __shared__ float lacc[2 * NB * G];
    int tid = threadIdx.x;
    for (int k = tid; k < 2 * NB * G; k += 256) lacc[k] = 0.f;
    __syncthreads();

    const int g = tid & 31;
    const int rsub = tid >> 5;
    int start = blockIdx.x * rows_per_block;
    int end = start + rows_per_block;
    if (end > N_TOTAL) end = N_TOTAL;

    float s[NB], ss[NB];
#pragma unroll
    for (int b = 0; b < NB; b++) { s[b] = 0.f; ss[b] = 0.f; }

    for (int row = start + rsub; row < end; row += 8) {
        int cl = cid[row];
        f4 v = ((const f4*)(feats + ((long long)row << 7)))[g];
        float rs = v.x + v.y + v.z + v.w;
        float rss = v.x * v.x + v.y * v.y + v.z * v.z + v.w * v.w;
#pragma unroll
        for (int b = 0; b < NB; b++) {
            if (cl == b) { s[b] += rs; ss[b] += rss; }
        }
    }
#pragma unroll
    for (int b = 0; b < NB; b++) {
        if (s[b] != 0.f || ss[b] != 0.f) {
            atomicAdd(&lacc[b * G + g], s[b]);
            atomicAdd(&lacc[NB * G + b * G + g], ss[b]);
        }
    }
    __syncthreads();

    for (int k = tid; k < 2 * NB * G; k += 256) {
        float a = lacc[k];
        if (a != 0.f) atomicAdd(&ws[k], a);
    }
}

// Pass C: finalize stats per block, then sequential normalize+affine.
// Non-temporal stores keep `out` from evicting feats in L3.
__global__ __launch_bounds__(256) void gn_apply(const float* __restrict__ feats,
                                                const unsigned char* __restrict__ cid,
                                                const float* __restrict__ gamma,
                                                const float* __restrict__ beta,
                                                const float* __restrict__ ws,
                                                float* __restrict__ out,
                                                int rows_per_block) {
    __shared__ float lmean[NB * G];
    __shared__ float linv[NB * G];
    int tid = threadIdx.x;
    {
        float sm = ws[tid];
        float sq = ws[NB * G + tid];
        float cnt = d_cnt[tid >> 5];
        float m = sm / cnt;
        float var = sq / cnt - m * m;
        lmean[tid] = m;
        linv[tid] = rsqrtf(var + EPS);
    }
    __syncthreads();

    const int g = tid & 31;
    const int rsub = tid >> 5;
    f4 gm = ((const f4*)gamma)[g];
    f4 bt = ((const f4*)beta)[g];

    int start = blockIdx.x * rows_per_block;
    int end = start + rows_per_block;
    if (end > N_TOTAL) end = N_TOTAL;

    for (int row = start + rsub; row < end; row += 8) {
        int cl = cid[row];
        f4 v = ((const f4*)(feats + ((long long)row << 7)))[g];
        float m = lmean[cl * G + g];
        float inv = linv[cl * G + g];
        f4 y;
        y.x = (v.x - m) * inv * gm.x + bt.x;
        y.y = (v.y - m) * inv * gm.y + bt.y;
        y.z = (v.z - m) * inv * gm.z + bt.z;
        y.w = (v.w - m) * inv * gm.w + bt.w;
        __builtin_nontemporal_store(y, (f4*)(out + ((long long)row << 7)) + g);
    }
}

extern "C" void kernel_launch(void* const* d_in, const int* in_sizes, int n_in,
                              void* d_out, int out_size, void* d_ws, size_t ws_size,
                              hipStream_t stream) {
    const float* feats = (const float*)d_in[0];
    const float* gamma = (const float*)d_in[1];
    const float* beta  = (const float*)d_in[2];
    const int*   perm  = (const int*)d_in[3];
    float* out = (float*)d_out;
    float* ws  = (float*)d_ws;
    unsigned char* cid = (unsigned char*)d_ws + 4096;

    gn_prep<<<512, 256, 0, stream>>>(perm, cid, ws);

    int rpb = (N_TOTAL + NBLK - 1) / NBLK;  // 245 rows per block
    gn_stats<<<NBLK, 256, 0, stream>>>(feats, cid, ws, rpb);
    gn_apply<<<NBLK, 256, 0, stream>>>(feats, cid, gamma, beta, ws, out, rpb);
}